// Round 7
// baseline (102.783 us; speedup 1.0000x reference)
//
#include <hip/hip_runtime.h>
#include <math.h>

#define NS   8      // samples
#define CC   256    // input channels
#define PP   961    // H*W
#define MM   7688   // NS*PP nodes
#define MP   7744   // MM padded to 64
#define HID  512
#define OUTC 256

typedef _Float16 h16;
using half8   = __attribute__((ext_vector_type(8))) _Float16;
using floatx4 = __attribute__((ext_vector_type(4))) float;

#define AS1 __attribute__((address_space(1)))
#define AS3 __attribute__((address_space(3)))

// deg = 963 for b in {0,7}, 964 otherwise; dinv = deg^-0.5
__device__ __forceinline__ float dinv_of(int b) {
    return (b == 0 || b == NS - 1) ? 0.0322245515f : 0.0322078318f;
}

// rho-layout row index: groups of 64 rows = 8 p-positions x all 8 samples
__device__ __forceinline__ int rho_of(int b, int p) {
    return ((p >> 3) << 6) + (b << 3) + (p & 7);
}

// K0 prep: [0,256): W1/W2 -> fp16; [256,2240): transpose-cast x -> Xt; [2240,2264): zero SZ/SY
__global__ void prep(const float* __restrict__ W1, const float* __restrict__ W2,
                     h16* __restrict__ w1h, h16* __restrict__ w2h,
                     const float* __restrict__ x, h16* __restrict__ Xt,
                     float* __restrict__ SZ, float* __restrict__ SY) {
    int blk = blockIdx.x, tid = threadIdx.x;
    if (blk < 256) {
        bool second = blk >= 128;
        const float* src = second ? W2 : W1;
        h16* dst = second ? w2h : w1h;
        int i = ((blk & 127) * 256 + tid) * 4;
        float4 v = *(const float4*)(src + i);
        dst[i + 0] = (h16)v.x; dst[i + 1] = (h16)v.y;
        dst[i + 2] = (h16)v.z; dst[i + 3] = (h16)v.w;
    } else if (blk < 2240) {
        // transpose-cast one 32(c) x 32(p) tile of sample b
        __shared__ h16 tr[32][33];
        int t = blk - 256;                       // < 1984 = 31(pt) * 8(ct) * 8(b)
        int b = t & 7, ct = (t >> 3) & 7, pt = t >> 6;
        int p0 = pt * 32, c0 = ct * 32;
        int j = tid & 31, i0 = tid >> 5;
        int p = p0 + j;
        #pragma unroll
        for (int r = 0; r < 4; ++r) {
            int c = c0 + i0 + r * 8;
            float v = (p < PP) ? x[((size_t)b * CC + c) * PP + p] : 0.f;
            tr[i0 + r * 8][j] = (h16)v;
        }
        __syncthreads();
        #pragma unroll
        for (int r = 0; r < 4; ++r) {
            int ii = tid & 31;
            int jj = (tid >> 5) + r * 8;
            int pw = p0 + jj;
            if (pw < PP)
                Xt[((size_t)b * PP + pw) * CC + c0 + ii] = tr[ii][jj];
        }
    } else {
        int i = (blk - 2240) * 256 + tid;        // < 6144
        if (i < NS * HID) SZ[i] = 0.f;
        else SY[i - NS * HID] = 0.f;
    }
}

// K1: MFMA GEMM (layer 1, raw): Z_rho = Xt @ W1^T, + per-sample colsums SZ.
// 64x64 tile, BK=64, XOR-swizzled LDS chunks. Output rows written at rho(m).
__global__ __launch_bounds__(256) void gemm1(
    const h16* __restrict__ A,    // Xt [MP][CC] natural layout
    const h16* __restrict__ B,    // w1h [HID][CC]
    h16* __restrict__ Z,          // [MP][HID] rho-layout
    float* __restrict__ SZ)       // [NS][HID]
{
    __shared__ __align__(16) h16 As[64 * 64];
    __shared__ __align__(16) h16 Bs[64 * 64];
    int tid = threadIdx.x, wave = tid >> 6, lane = tid & 63;
    int m0 = blockIdx.x * 64, n0 = blockIdx.y * 64;
    int sro = lane >> 3;
    int sch = (lane & 7) ^ sro;
    const h16* ga0 = A + (size_t)(m0 + wave * 16 + sro) * CC + sch * 8;
    const h16* gb0 = B + (size_t)(n0 + wave * 16 + sro) * CC + sch * 8;
    h16* la0 = &As[(wave * 16) * 64];
    h16* la1 = &As[(wave * 16 + 8) * 64];
    h16* lb0 = &Bs[(wave * 16) * 64];
    h16* lb1 = &Bs[(wave * 16 + 8) * 64];
    int fr = lane & 15, fq = lane >> 4;
    floatx4 acc[4] = {{0.f,0.f,0.f,0.f},{0.f,0.f,0.f,0.f},{0.f,0.f,0.f,0.f},{0.f,0.f,0.f,0.f}};
    for (int kk = 0; kk < CC; kk += 64) {
        __builtin_amdgcn_global_load_lds((const AS1 void*)(const void*)(ga0 + kk),
                                         (AS3 void*)(void*)la0, 16, 0, 0);
        __builtin_amdgcn_global_load_lds((const AS1 void*)(const void*)(ga0 + 8 * CC + kk),
                                         (AS3 void*)(void*)la1, 16, 0, 0);
        __builtin_amdgcn_global_load_lds((const AS1 void*)(const void*)(gb0 + kk),
                                         (AS3 void*)(void*)lb0, 16, 0, 0);
        __builtin_amdgcn_global_load_lds((const AS1 void*)(const void*)(gb0 + 8 * CC + kk),
                                         (AS3 void*)(void*)lb1, 16, 0, 0);
        __syncthreads();
        #pragma unroll
        for (int ks = 0; ks < 2; ++ks) {
            int slot = (ks * 4 + fq) ^ (fr & 7);
            half8 bf = *(const half8*)&Bs[(wave * 16 + fr) * 64 + slot * 8];
            #pragma unroll
            for (int mb = 0; mb < 4; ++mb) {
                half8 af = *(const half8*)&As[(mb * 16 + fr) * 64 + slot * 8];
                acc[mb] = __builtin_amdgcn_mfma_f32_16x16x32_f16(af, bf, acc[mb], 0, 0, 0);
            }
        }
        __syncthreads();
    }
    int col = n0 + wave * 16 + fr;
    float s_lo = 0.f, s_hi = 0.f;
    int blo = m0 / 961;
    int mcut = (blo + 1) * 961;
    #pragma unroll
    for (int mb = 0; mb < 4; ++mb) {
        #pragma unroll
        for (int r = 0; r < 4; ++r) {
            int m = m0 + mb * 16 + fq * 4 + r;
            if (m < MM) {
                float v = acc[mb][r];
                int b = m / 961;
                int p = m - b * 961;
                Z[(size_t)rho_of(b, p) * HID + col] = (h16)v;
                if (m < mcut) s_lo += v; else s_hi += v;
            }
        }
    }
    s_lo += __shfl_xor(s_lo, 16);
    s_lo += __shfl_xor(s_lo, 32);
    s_hi += __shfl_xor(s_hi, 16);
    s_hi += __shfl_xor(s_hi, 32);
    if (fq == 0) {
        atomicAdd(&SZ[blo * HID + col], s_lo);
        int bhi = (m0 + 63) / 961;
        if (bhi != blo && bhi < NS) atomicAdd(&SZ[bhi * HID + col], s_hi);
    }
}

// K2: fused apply1 + GEMM2 in rho-layout. One Z-slice staged per K-step; the
// b+-1 neighbors are rows +-8 IN-TILE (same low-3 bits -> same XOR slot).
// H = lrelu(b1 + db^2*(SZ+Z) + db*dm*Z[row-8] + db*dp*Z[row+8]) computed in LDS,
// then MFMA vs W2. Y (raw) + per-sample colsums SY. Invalid p rows (pt=120
// junk) force H=0 -> Y rows 0, SY contribution 0 (no epilogue masking needed).
__global__ __launch_bounds__(256) void gemm2_rho(
    const h16* __restrict__ Z,     // [MP][HID] rho-layout
    const h16* __restrict__ B,     // w2h [OUTC][HID]
    const float* __restrict__ SZ,  // [NS][HID]
    const float* __restrict__ b1v, // [HID]
    float* __restrict__ Y,         // [MP][OUTC] rho-layout
    float* __restrict__ SY)        // [NS][OUTC]
{
    __shared__ __align__(16) h16 Zs[64 * 64];
    __shared__ __align__(16) h16 Hs[64 * 64];
    __shared__ __align__(16) h16 Bs[64 * 64];
    int tid = threadIdx.x, wave = tid >> 6, lane = tid & 63;
    int rt = blockIdx.x;                  // rho row-tile: rows [rt*64, rt*64+64)
    int n0 = blockIdx.y * 64;
    int sro = lane >> 3;
    int sch = (lane & 7) ^ sro;
    const h16* gz0 = Z + (size_t)(rt * 64 + wave * 16 + sro) * HID + sch * 8;
    const h16* gb0 = B + (size_t)(n0 + wave * 16 + sro) * HID + sch * 8;
    h16* lz0 = &Zs[(wave * 16) * 64];
    h16* lz1 = &Zs[(wave * 16 + 8) * 64];
    h16* lb0 = &Bs[(wave * 16) * 64];
    h16* lb1 = &Bs[(wave * 16 + 8) * 64];
    int fr = lane & 15, fq = lane >> 4;
    // H-compute mapping: thread -> row hr, chunks hc0, hc0+1
    int hr = tid >> 2;                    // 0..63;  b = hr>>3, psub = hr&7
    int hc0 = (tid & 3) * 2;
    int hb = hr >> 3;
    bool pvalid = (rt * 8 + (hr & 7)) < PP;
    float db  = dinv_of(hb);
    float dmw = (hb > 0)      ? db * dinv_of(hb - 1) : 0.f;
    float dpw = (hb < NS - 1) ? db * dinv_of(hb + 1) : 0.f;
    float db2 = db * db;
    int hrm = (hb > 0)      ? hr - 8 : hr;   // clamped: coeff is 0 anyway
    int hrp = (hb < NS - 1) ? hr + 8 : hr;
    floatx4 acc[4] = {{0.f,0.f,0.f,0.f},{0.f,0.f,0.f,0.f},{0.f,0.f,0.f,0.f},{0.f,0.f,0.f,0.f}};
    for (int kk = 0; kk < HID; kk += 64) {
        __builtin_amdgcn_global_load_lds((const AS1 void*)(const void*)(gz0 + kk),
                                         (AS3 void*)(void*)lz0, 16, 0, 0);
        __builtin_amdgcn_global_load_lds((const AS1 void*)(const void*)(gz0 + 8 * HID + kk),
                                         (AS3 void*)(void*)lz1, 16, 0, 0);
        __builtin_amdgcn_global_load_lds((const AS1 void*)(const void*)(gb0 + kk),
                                         (AS3 void*)(void*)lb0, 16, 0, 0);
        __builtin_amdgcn_global_load_lds((const AS1 void*)(const void*)(gb0 + 8 * HID + kk),
                                         (AS3 void*)(void*)lb1, 16, 0, 0);
        __syncthreads();
        #pragma unroll
        for (int qi = 0; qi < 2; ++qi) {
            int ch = hc0 + qi;
            int slot = ch ^ (hr & 7);     // same slot valid for hr, hr+-8
            half8 zc = *(const half8*)&Zs[hr  * 64 + slot * 8];
            half8 zm = *(const half8*)&Zs[hrm * 64 + slot * 8];
            half8 zp = *(const half8*)&Zs[hrp * 64 + slot * 8];
            int h0 = kk + ch * 8;
            float4 s0  = *(const float4*)(SZ + hb * HID + h0);
            float4 s1  = *(const float4*)(SZ + hb * HID + h0 + 4);
            float4 bb0 = *(const float4*)(b1v + h0);
            float4 bb1 = *(const float4*)(b1v + h0 + 4);
            float ss[8] = {s0.x, s0.y, s0.z, s0.w, s1.x, s1.y, s1.z, s1.w};
            float bb[8] = {bb0.x, bb0.y, bb0.z, bb0.w, bb1.x, bb1.y, bb1.z, bb1.w};
            half8 o;
            #pragma unroll
            for (int j = 0; j < 8; ++j) {
                float v = db2 * (ss[j] + (float)zc[j])
                        + dmw * (float)zm[j] + dpw * (float)zp[j] + bb[j];
                v = (v >= 0.f) ? v : 0.01f * v;
                o[j] = pvalid ? (h16)v : (h16)0.f;
            }
            *(half8*)&Hs[hr * 64 + slot * 8] = o;
        }
        __syncthreads();
        #pragma unroll
        for (int ks = 0; ks < 2; ++ks) {
            int slot = (ks * 4 + fq) ^ (fr & 7);
            half8 bf = *(const half8*)&Bs[(wave * 16 + fr) * 64 + slot * 8];
            #pragma unroll
            for (int mb = 0; mb < 4; ++mb) {
                half8 af = *(const half8*)&Hs[(mb * 16 + fr) * 64 + slot * 8];
                acc[mb] = __builtin_amdgcn_mfma_f32_16x16x32_f16(af, bf, acc[mb], 0, 0, 0);
            }
        }
        __syncthreads();
    }
    // epilogue: Y write + SY sums. acc row = 16*mb + 4*fq + r -> b = 2*mb + (fq>=2)
    int col = n0 + wave * 16 + fr;
    size_t row0 = (size_t)rt * 64;
    float sb[4];
    #pragma unroll
    for (int mb = 0; mb < 4; ++mb) {
        float s = 0.f;
        #pragma unroll
        for (int r = 0; r < 4; ++r) {
            int row = 16 * mb + 4 * fq + r;
            float v = acc[mb][r];
            Y[(row0 + row) * OUTC + col] = v;
            s += v;
        }
        sb[mb] = s;
    }
    #pragma unroll
    for (int mb = 0; mb < 4; ++mb) sb[mb] += __shfl_xor(sb[mb], 16);
    if (fq == 0 || fq == 2) {
        int bodd = (fq >= 2) ? 1 : 0;
        #pragma unroll
        for (int mb = 0; mb < 4; ++mb)
            atomicAdd(&SY[(2 * mb + bodd) * OUTC + col], sb[mb]);
    }
}

// K3: out[o*PP+p] = max_b lrelu( b2[o] + db*( db*(SY[b,o]+Y[b,p,o]) + dm*Y[b-1,p,o] + dp*Y[b+1,p,o] ) )
// Y in rho-layout: row(b,p) = (p>>3)*64 + b*8 + (p&7)
__global__ void final_max(const float* __restrict__ Y, const float* __restrict__ SY,
                          const float* __restrict__ b2, float* __restrict__ out) {
    int pt = blockIdx.x, ot = blockIdx.y;
    int p0 = pt * 32, o0 = ot * 32;
    __shared__ float t[32][33];
    int i = threadIdx.x & 31, j0 = threadIdx.x >> 5;
    int o = o0 + i;
    float bias = b2[o];
    #pragma unroll
    for (int r = 0; r < 4; ++r) {
        int j = j0 + r * 8;
        int p = p0 + j;
        float vmax = -INFINITY;
        if (p < PP) {
            size_t rbase = (size_t)(((p >> 3) << 6) + (p & 7)) * OUTC + o;
            float y[NS];
            #pragma unroll
            for (int b = 0; b < NS; ++b)
                y[b] = Y[rbase + (size_t)b * 8 * OUTC];
            #pragma unroll
            for (int b = 0; b < NS; ++b) {
                float db = dinv_of(b);
                float a = db * (SY[b * OUTC + o] + y[b]);
                if (b > 0)      a += dinv_of(b - 1) * y[b - 1];
                if (b < NS - 1) a += dinv_of(b + 1) * y[b + 1];
                float z = db * a + bias;
                z = (z >= 0.f) ? z : 0.01f * z;
                vmax = fmaxf(vmax, z);
            }
        }
        t[j][i] = vmax;
    }
    __syncthreads();
    int jj = threadIdx.x & 31, ii0 = threadIdx.x >> 5;
    #pragma unroll
    for (int r = 0; r < 4; ++r) {
        int ii = ii0 + r * 8;
        int pw = p0 + jj;
        if (pw < PP)
            out[(size_t)(o0 + ii) * PP + pw] = t[jj][ii];
    }
}

extern "C" void kernel_launch(void* const* d_in, const int* in_sizes, int n_in,
                              void* d_out, int out_size, void* d_ws, size_t ws_size,
                              hipStream_t stream) {
    const float* x  = (const float*)d_in[0];
    const float* W1 = (const float*)d_in[1];
    const float* b1 = (const float*)d_in[2];
    const float* W2 = (const float*)d_in[3];
    const float* b2 = (const float*)d_in[4];
    float* out = (float*)d_out;
    float* ws  = (float*)d_ws;

    // workspace layout (float offsets, 16B-aligned)
    float* SZ  = ws;                             //     4,096 f
    float* SY  = ws + 4096;                      //     2,048 f
    h16*  w1h  = (h16*)(ws + 6144);              //  131,072 h = 65,536 f
    h16*  w2h  = (h16*)(ws + 71680);             //  131,072 h
    h16*  Xt   = (h16*)(ws + 137216);            //  MP*CC  h = 991,232 f (pad rows stay poison: finite, masked)
    h16*  Z    = (h16*)(ws + 1128448);           //  MP*HID h = 1,982,464 f (rho-layout)
    float* Y   = ws + 3110912;                   //  MP*OUTC f = 1,982,464 f -> end 5,093,376 f (20.4 MB)

    prep<<<2264, 256, 0, stream>>>(W1, W2, w1h, w2h, x, Xt, SZ, SY);
    gemm1<<<dim3(MP / 64, HID / 64), 256, 0, stream>>>(Xt, w1h, Z, SZ);
    gemm2_rho<<<dim3(MP / 64, OUTC / 64), 256, 0, stream>>>(Z, w2h, SZ, b1, Y, SY);
    final_max<<<dim3(31, 8), 256, 0, stream>>>(Y, SY, b2, out);
}